// Round 3
// baseline (502.719 us; speedup 1.0000x reference)
//
#include <hip/hip_runtime.h>
#include <hip/hip_bf16.h>

typedef __attribute__((ext_vector_type(4))) float  f32x4;
typedef __attribute__((ext_vector_type(8))) short  short8;

#define GAS(p) ((const __attribute__((address_space(1))) void*)(p))
#define LAS(p) ((__attribute__((address_space(3))) void*)(p))

__device__ inline short bf16_of(float f) {
    union { float f; unsigned u; } v; v.f = f;
    unsigned r = v.u + 0x7FFFu + ((v.u >> 16) & 1u);   // RNE
    return (short)(r >> 16);
}
__device__ inline float f_of_bf16(short h) {
    union { unsigned u; float f; } v; v.u = ((unsigned)(unsigned short)h) << 16;
    return v.f;
}

// ============================================================================
// GEMM core: 128x128 tile, BK=64, 4 waves, global_load_lds staging into
// linear LDS [128][64] with XOR-swizzle (source pre-swizzled, reads swizzled),
// double-buffered, one barrier pair per K-step (32 MFMA between barriers).
// C = A * B^T ; A row-major [.,lda], B row-major [.,ldb].
// ============================================================================
__device__ __forceinline__ void stage64(const short* A, long lda,
                                        const short* B, long ldb,
                                        short* As, short* Bs) {
    const int tid = threadIdx.x;
    const int w = tid >> 6, l = tid & 63;
    const int r = l >> 3;                              // row within 8-row group
    const int scol = ((l & 7) ^ r) * 8;                // pre-swizzled source col
#pragma unroll
    for (int q = 0; q < 4; ++q) {
        const int rowb = q * 32 + w * 8;
        __builtin_amdgcn_global_load_lds(GAS(A + (long)(rowb + r) * lda + scol),
                                         LAS(As + rowb * 64), 16, 0, 0);
        __builtin_amdgcn_global_load_lds(GAS(B + (long)(rowb + r) * ldb + scol),
                                         LAS(Bs + rowb * 64), 16, 0, 0);
    }
}

__device__ __forceinline__ void gemm_core64(const short* A, long lda,
                                            const short* B, long ldb, int nk,
                                            short* sA, short* sB,  // [2][8192] each
                                            f32x4 acc[4][4]) {
    const int tid = threadIdx.x;
    const int lane = tid & 63, wid = tid >> 6;
    const int wr = wid >> 1, wc = wid & 1;
    const int fr = lane & 15, fk = lane >> 4;
    const int swz = (fr & 7) << 4;                     // byte-XOR within row
    const int abase = (wr * 64 + fr) * 128 + fk * 16;  // bytes
    const int bbase = (wc * 64 + fr) * 128 + fk * 16;

    stage64(A, lda, B, ldb, sA, sB);
    __syncthreads();
    for (int ks = 0; ks < nk; ++ks) {
        const int cur = ks & 1;
        if (ks + 1 < nk)
            stage64(A + (ks + 1) * 64, lda, B + (ks + 1) * 64, ldb,
                    sA + (cur ^ 1) * 8192, sB + (cur ^ 1) * 8192);
        const char* pa = (const char*)(sA + cur * 8192);
        const char* pb = (const char*)(sB + cur * 8192);
        short8 af[2][4], bf[2][4];
#pragma unroll
        for (int kk = 0; kk < 2; ++kk) {
#pragma unroll
            for (int mi = 0; mi < 4; ++mi)
                af[kk][mi] = *(const short8*)(pa + (((abase + kk * 64) ^ swz) + mi * 2048));
#pragma unroll
            for (int ni = 0; ni < 4; ++ni)
                bf[kk][ni] = *(const short8*)(pb + (((bbase + kk * 64) ^ swz) + ni * 2048));
        }
#pragma unroll
        for (int kk = 0; kk < 2; ++kk)
#pragma unroll
            for (int mi = 0; mi < 4; ++mi)
#pragma unroll
                for (int ni = 0; ni < 4; ++ni)
                    acc[mi][ni] = __builtin_amdgcn_mfma_f32_16x16x32_bf16(af[kk][mi], bf[kk][ni], acc[mi][ni], 0, 0, 0);
        __syncthreads();
    }
}

// ---- bounce a 128x128 bf16 tile (values in vals[mi][ni][r]) through LDS and
// ---- store coalesced to C (ldc in elems). Call AFTER k-loop (sA free, 32KB).
__device__ __forceinline__ void bounce_store(short* Pb, const short vals[4][4][4],
                                             short* C, long ldc) {
    const int tid = threadIdx.x, lane = tid & 63, wid = tid >> 6;
    const int wr = wid >> 1, wc = wid & 1, fr = lane & 15, fk = lane >> 4;
#pragma unroll
    for (int mi = 0; mi < 4; ++mi)
#pragma unroll
        for (int ni = 0; ni < 4; ++ni)
#pragma unroll
            for (int r = 0; r < 4; ++r) {
                const int row = wr * 64 + mi * 16 + fk * 4 + r;
                const int col = wc * 64 + ni * 16 + fr;
                Pb[row * 128 + (col ^ ((row & 7) << 3))] = vals[mi][ni][r];
            }
    __syncthreads();
#pragma unroll
    for (int i = 0; i < 8; ++i) {
        const int row = i * 16 + (tid >> 4);
        const int ch = tid & 15;
        short8 v = *(const short8*)&Pb[row * 128 + ((ch * 8) ^ ((row & 7) << 3))];
        *(short8*)&C[(long)row * ldc + ch * 8] = v;
    }
}

// ---------- generic bf16-out GEMM + bias (projections) ----------
template<int BIAS>   // 0 none, 1 bias[col], 2 bias[row]
__global__ __launch_bounds__(256, 2)
void gemm_bias16(const short* __restrict__ A, long lda, const short* __restrict__ B, long ldb,
                 short* __restrict__ C, long ldc, const float* __restrict__ bias, int nk) {
    __shared__ short sA[2 * 8192], sB[2 * 8192];
    const short* Ab = A + (long)blockIdx.x * 128 * lda;
    const short* Bb = B + (long)blockIdx.y * 128 * ldb;
    f32x4 acc[4][4] = {};
    gemm_core64(Ab, lda, Bb, ldb, nk, sA, sB, acc);

    const int lane = threadIdx.x & 63, wid = threadIdx.x >> 6;
    const int wr = wid >> 1, wc = wid & 1, fr = lane & 15, fk = lane >> 4;
    const long r0 = (long)blockIdx.x * 128, c0 = (long)blockIdx.y * 128;
    short vals[4][4][4];
#pragma unroll
    for (int mi = 0; mi < 4; ++mi)
#pragma unroll
        for (int ni = 0; ni < 4; ++ni)
#pragma unroll
            for (int r = 0; r < 4; ++r) {
                float v = acc[mi][ni][r];
                if (BIAS == 1) v += bias[c0 + wc * 64 + ni * 16 + fr];
                if (BIAS == 2) v += bias[r0 + wr * 64 + mi * 16 + fk * 4 + r];
                vals[mi][ni][r] = bf16_of(v);
            }
    bounce_store(sA, vals, C + r0 * ldc + c0, ldc);
}

// ---------- f32-out GEMM + bias / accumulate (final projection) ----------
template<bool ACC>
__global__ __launch_bounds__(256, 2)
void gemm_f32(const short* __restrict__ A, long lda, const short* __restrict__ B, long ldb,
              float* __restrict__ C, long ldc, const float* __restrict__ bias, int nk) {
    __shared__ short sA[2 * 8192], sB[2 * 8192];
    const short* Ab = A + (long)blockIdx.x * 128 * lda;
    const short* Bb = B + (long)blockIdx.y * 128 * ldb;
    f32x4 acc[4][4] = {};
    gemm_core64(Ab, lda, Bb, ldb, nk, sA, sB, acc);

    const int lane = threadIdx.x & 63, wid = threadIdx.x >> 6;
    const int wr = wid >> 1, wc = wid & 1, fr = lane & 15, fk = lane >> 4;
    const long r0 = (long)blockIdx.x * 128 + wr * 64 + fk * 4;
    const long c0 = (long)blockIdx.y * 128 + wc * 64 + fr;
#pragma unroll
    for (int mi = 0; mi < 4; ++mi)
#pragma unroll
        for (int ni = 0; ni < 4; ++ni) {
            const long rr = r0 + mi * 16, cc = c0 + ni * 16;
#pragma unroll
            for (int r = 0; r < 4; ++r) {
                float v = acc[mi][ni][r];
                if (!ACC) v += bias[cc];
                const long idx = (rr + r) * ldc + cc;
                if (ACC) v += C[idx];
                C[idx] = v;
            }
        }
}

// ---------- QK^T -> exp2 -> partial row sums + bf16 P store ----------
struct Off6 { long a[6], b[6]; };

__global__ __launch_bounds__(256, 2)
void qk_exp(const short* __restrict__ Q, const short* __restrict__ K,
            short* __restrict__ Sc, float* __restrict__ lpart,
            Off6 o, int z0, float kscale) {
    __shared__ short sA[2 * 8192], sB[2 * 8192];
    const int slice = z0 + blockIdx.z;
    const int gp = slice >> 2, b = slice & 3;
    const short* Ab = Q + o.a[gp] + ((long)b * 2048 + (long)blockIdx.x * 128) * 512;
    const short* Bb = K + o.b[gp] + ((long)b * 2048 + (long)blockIdx.y * 128) * 512;
    f32x4 acc[4][4] = {};
    gemm_core64(Ab, 512, Bb, 512, 8, sA, sB, acc);

    const int tid = threadIdx.x, lane = tid & 63, wid = tid >> 6;
    const int wr = wid >> 1, wc = wid & 1, fr = lane & 15, fk = lane >> 4;

#pragma unroll
    for (int mi = 0; mi < 4; ++mi)
#pragma unroll
        for (int ni = 0; ni < 4; ++ni)
#pragma unroll
            for (int r = 0; r < 4; ++r)
                acc[mi][ni][r] = exp2f(acc[mi][ni][r] * kscale);

    // per-row partial sums over this wave's 64 cols -> lpart[slice][by*2+wc][row]
#pragma unroll
    for (int mi = 0; mi < 4; ++mi)
#pragma unroll
        for (int r = 0; r < 4; ++r) {
            float s = acc[mi][0][r] + acc[mi][1][r] + acc[mi][2][r] + acc[mi][3][r];
            s += __shfl_xor(s, 1); s += __shfl_xor(s, 2);
            s += __shfl_xor(s, 4); s += __shfl_xor(s, 8);
            if (fr == 0)
                lpart[((long)slice * 32 + blockIdx.y * 2 + wc) * 2048 +
                      (long)blockIdx.x * 128 + wr * 64 + mi * 16 + fk * 4 + r] = s;
        }

    short vals[4][4][4];
#pragma unroll
    for (int mi = 0; mi < 4; ++mi)
#pragma unroll
        for (int ni = 0; ni < 4; ++ni)
#pragma unroll
            for (int r = 0; r < 4; ++r)
                vals[mi][ni][r] = bf16_of(acc[mi][ni][r]);

    short* Cb = Sc + (long)blockIdx.z * 2048 * 2048 +
                (long)blockIdx.x * 128 * 2048 + (long)blockIdx.y * 128;
    bounce_store(sA, vals, Cb, 2048);
}

// ---------- reduce 32 partials -> l ----------
__global__ __launch_bounds__(256)
void lred(const float* __restrict__ lpart, float* __restrict__ l, int z0) {
    const int slice = z0 + (blockIdx.x >> 3);
    const int row = (blockIdx.x & 7) * 256 + threadIdx.x;
    float s = 0.f;
#pragma unroll
    for (int j = 0; j < 32; ++j)
        s += lpart[((long)slice * 32 + j) * 2048 + row];
    l[(long)slice * 2048 + row] = s;
}

// ---------- P @ V with fused 1/l normalize ----------
struct POff { long v[6], c[6]; int f2[6]; };

__global__ __launch_bounds__(256, 2)
void pv_div(const short* __restrict__ Sc, const short* __restrict__ VT,
            const float* __restrict__ l, short* __restrict__ F1,
            short* __restrict__ F2, POff o, int z0) {
    __shared__ short sA[2 * 8192], sB[2 * 8192];
    const int slice = z0 + blockIdx.z;
    const int gp = slice >> 2, b = slice & 3;
    const short* Ab = Sc + (long)blockIdx.z * 2048 * 2048 + (long)blockIdx.x * 128 * 2048;
    const short* Bb = VT + o.v[gp] + (long)b * 2048 + (long)blockIdx.y * 128 * 24576;
    f32x4 acc[4][4] = {};
    gemm_core64(Ab, 2048, Bb, 24576, 32, sA, sB, acc);

    const int tid = threadIdx.x, lane = tid & 63, wid = tid >> 6;
    const int wr = wid >> 1, wc = wid & 1, fr = lane & 15, fk = lane >> 4;
    const float* lb = l + (long)slice * 2048 + (long)blockIdx.x * 128;

    short vals[4][4][4];
#pragma unroll
    for (int mi = 0; mi < 4; ++mi) {
        float linv[4];
#pragma unroll
        for (int r = 0; r < 4; ++r)
            linv[r] = 1.0f / lb[wr * 64 + mi * 16 + fk * 4 + r];
#pragma unroll
        for (int ni = 0; ni < 4; ++ni)
#pragma unroll
            for (int r = 0; r < 4; ++r)
                vals[mi][ni][r] = bf16_of(acc[mi][ni][r] * linv[r]);
    }

    short* F = (o.f2[gp] ? F2 : F1);
    short* Cb = F + ((long)b * 2048 + (long)blockIdx.x * 128) * 1536 +
                o.c[gp] + (long)blockIdx.y * 128;
    bounce_store(sA, vals, Cb, 1536);
}

// ---------- f32 -> bf16 convert of x1,x2,x3 ----------
__global__ __launch_bounds__(256)
void xconv(const float* __restrict__ x0, const float* __restrict__ x1,
           const float* __restrict__ x2, short* __restrict__ xb) {
    const float* s = blockIdx.z == 0 ? x0 : (blockIdx.z == 1 ? x1 : x2);
    const long i = ((long)blockIdx.x * 256 + threadIdx.x) * 8;
    f32x4 a = *(const f32x4*)(s + i), c = *(const f32x4*)(s + i + 4);
    short8 v;
    v[0] = bf16_of(a.x); v[1] = bf16_of(a.y); v[2] = bf16_of(a.z); v[3] = bf16_of(a.w);
    v[4] = bf16_of(c.x); v[5] = bf16_of(c.y); v[6] = bf16_of(c.z); v[7] = bf16_of(c.w);
    *(short8*)(xb + (long)blockIdx.z * 8192 * 512 + i) = v;
}

// ---------- transpose f32 -> bf16 (weights) ----------
__global__ __launch_bounds__(256)
void transpose_to_bf16(const float* __restrict__ src, short* __restrict__ dst,
                       int rows, int cols) {
    __shared__ float t[32][33];
    const int lx = threadIdx.x & 31, ly = threadIdx.x >> 5;
    const int r0 = blockIdx.x * 32, c0 = blockIdx.y * 32;
#pragma unroll
    for (int p = 0; p < 4; ++p)
        t[ly + 8 * p][lx] = src[(long)(r0 + ly + 8 * p) * cols + (c0 + lx)];
    __syncthreads();
#pragma unroll
    for (int p = 0; p < 4; ++p)
        dst[(long)(c0 + ly + 8 * p) * rows + (r0 + lx)] = bf16_of(t[lx][ly + 8 * p]);
}

// ============================================================================
extern "C" void kernel_launch(void* const* d_in, const int* in_sizes, int n_in,
                              void* d_out, int out_size, void* d_ws, size_t ws_size,
                              hipStream_t stream) {
    const float* x[3] = { (const float*)d_in[0], (const float*)d_in[1], (const float*)d_in[2] };
    const float* Wq = (const float*)d_in[3]; const float* bq = (const float*)d_in[4];
    const float* Wk = (const float*)d_in[5]; const float* bk = (const float*)d_in[6];
    const float* Wv = (const float*)d_in[7]; const float* bv = (const float*)d_in[8];
    const float* Wo = (const float*)d_in[9]; const float* bo = (const float*)d_in[10];

    const long TOK = 8192, T3 = 3 * TOK;

    char* ws = (char*)d_ws;
    size_t off = 0;
    auto alloc = [&](size_t bytes) -> void* {
        void* pp = ws + off;
        off += (bytes + 255) & ~(size_t)255;
        return pp;
    };

    short* WqT = (short*)alloc(512L * 512 * 2);
    short* WkT = (short*)alloc(512L * 512 * 2);
    short* WvT = (short*)alloc(512L * 512 * 2);
    short* WoT = (short*)alloc(512L * 1536 * 2);
    short* Qb  = (short*)alloc(T3 * 512 * 2);
    short* Kb  = (short*)alloc(T3 * 512 * 2);
    short* VT  = (short*)alloc(512L * T3 * 2);            // [512][24576]
    short* fused1 = (short*)alloc(TOK * 1536 * 2);
    short* fused2 = (short*)alloc(TOK * 1536 * 2);
    float* l    = (float*)alloc(24L * 2048 * 4);
    float* lpart = (float*)alloc(24L * 32 * 2048 * 4);
    short* xb   = (short*)alloc(T3 * 512 * 2);

    const size_t SLICE = 2048L * 2048 * 2;                // 8.39 MB
    int nsl;
    if      (ws_size >= off + 24 * SLICE) nsl = 24;
    else if (ws_size >= off + 12 * SLICE) nsl = 12;
    else                                  nsl = 4;
    short* scores = (short*)alloc((size_t)nsl * SLICE);

    const dim3 tb(256);
    transpose_to_bf16<<<dim3(16, 16), tb, 0, stream>>>(Wq, WqT, 512, 512);
    transpose_to_bf16<<<dim3(16, 16), tb, 0, stream>>>(Wk, WkT, 512, 512);
    transpose_to_bf16<<<dim3(16, 16), tb, 0, stream>>>(Wv, WvT, 512, 512);
    transpose_to_bf16<<<dim3(48, 16), tb, 0, stream>>>(Wo, WoT, 1536, 512);
    xconv<<<dim3(2048, 1, 3), tb, 0, stream>>>(x[0], x[1], x[2], xb);

    gemm_bias16<1><<<dim3(192, 4), tb, 0, stream>>>(xb, 512, WqT, 512, Qb, 512, bq, 8);
    gemm_bias16<1><<<dim3(192, 4), tb, 0, stream>>>(xb, 512, WkT, 512, Kb, 512, bk, 8);
    gemm_bias16<2><<<dim3(4, 192), tb, 0, stream>>>(WvT, 512, xb, 512, VT, T3, bv, 8);

    // pairs: i attends to j. gp 0..2 -> fused1, gp 3..5 -> fused2 (no RMW).
    const int imap[6] = {0, 1, 2, 0, 1, 2};
    const int jmap[6] = {1, 0, 0, 2, 2, 1};
    Off6 qo{}; POff po{};
    for (int gp = 0; gp < 6; ++gp) {
        qo.a[gp] = (long)imap[gp] * TOK * 512;
        qo.b[gp] = (long)jmap[gp] * TOK * 512;
        po.v[gp] = (long)jmap[gp] * TOK;      // col offset within VT row
        po.c[gp] = (long)imap[gp] * 512;      // col offset within fused
        po.f2[gp] = (gp >= 3);
    }
    const float kscale = 0.04419417382415922f * 1.4426950408889634f;

    for (int z0 = 0; z0 < 24; z0 += nsl) {
        qk_exp<<<dim3(16, 16, nsl), tb, 0, stream>>>(Qb, Kb, scores, lpart, qo, z0, kscale);
        lred<<<dim3(nsl * 8), tb, 0, stream>>>(lpart, l, z0);
        pv_div<<<dim3(16, 4, nsl), tb, 0, stream>>>(scores, VT, l, fused1, fused2, po, z0);
    }

    gemm_f32<false><<<dim3(64, 4), tb, 0, stream>>>(fused1, 1536, WoT, 1536, (float*)d_out, 512, bo, 24);
    gemm_f32<true><<<dim3(64, 4), tb, 0, stream>>>(fused2, 1536, WoT, 1536, (float*)d_out, 512, nullptr, 24);
}